// Round 7
// baseline (417.885 us; speedup 1.0000x reference)
//
#include <hip/hip_runtime.h>
#include <cmath>

#define SLEN 2048

typedef __bf16 bf16x8 __attribute__((ext_vector_type(8)));
typedef float  f32x4  __attribute__((ext_vector_type(4)));

__device__ inline void gld16(const void* g, void* l) {
    __builtin_amdgcn_global_load_lds(
        (const __attribute__((address_space(1))) void*)(uintptr_t)g,
        (__attribute__((address_space(3))) void*)(unsigned)(uintptr_t)l, 16, 0, 0);
}

// ---------------------------------------------------------------------------
// One-launch fp32->bf16 convert of all 9 inputs (segment table by value).
// ---------------------------------------------------------------------------
struct CvArgs {
    const float* src[9];
    __bf16*      dst[9];
    long         cum[10];
};
__global__ __launch_bounds__(256)
void convert_all(CvArgs a) {
    long i8 = ((long)blockIdx.x * 256 + threadIdx.x) * 8;
    if (i8 >= a.cum[9]) return;
    int s = 0;
#pragma unroll
    for (int k = 1; k < 9; k++) if (i8 >= a.cum[k]) s = k;
    long loc = i8 - a.cum[s];
    const float* sp = a.src[s] + loc;
    float4 u0 = *(const float4*)(sp);
    float4 u1 = *(const float4*)(sp + 4);
    bf16x8 o;
    o[0] = (__bf16)u0.x; o[1] = (__bf16)u0.y; o[2] = (__bf16)u0.z; o[3] = (__bf16)u0.w;
    o[4] = (__bf16)u1.x; o[5] = (__bf16)u1.y; o[6] = (__bf16)u1.z; o[7] = (__bf16)u1.w;
    *(bf16x8*)(a.dst[s] + loc) = o;
}

// ---------------------------------------------------------------------------
// NT GEMM, 128x128x64 tiles, 4 waves, global_load_lds + XOR-swizzled LDS.
// v0 structure (proven best for this 2-phase shape) + launch_bounds(256,3)
// (round-5: neutral-to-slightly-better).
// Epilogue modes:
//  2: fp32 [M,N] row-major (final output)
//  8: down-proj merged: col<1536 -> c_q; col<2048 -> c_kv; tile n0==2048 ->
//     k-rope (rotate pairs i/i+32, broadcast 16 heads into k_all)
//  9: up-Q merged (scaled by `scale`): col<2048 -> q_all nope scatter;
//     col>=2048 -> q-rope into q_all[...,128:192]
// 10: up-KV merged: col<2048 -> k_all nope scatter; col>=2048 -> V transpose
// ---------------------------------------------------------------------------
struct Outs { __bf16* a; __bf16* b; __bf16* c; float* f; };

__global__ __launch_bounds__(256, 3)
void gemm_nt(const __bf16* __restrict__ A, const __bf16* __restrict__ B,
             Outs o, const int* __restrict__ positions,
             int M, int N, int K, int mode, float scale) {
    __shared__ __bf16 As[128 * 64];
    __shared__ __bf16 Bs[128 * 64];
    int tid = threadIdx.x;
    int wave = tid >> 6, lane = tid & 63;
    int lane15 = lane & 15, quad = lane >> 4;
    int ri = lane >> 3, ci = lane & 7;
    int cg = ci ^ ri;
    int m0 = blockIdx.x * 128, n0 = blockIdx.y * 128;
    int wm = (wave & 1) * 64, wn = (wave >> 1) * 64;
    f32x4 acc[4][4] = {};

    for (int k0 = 0; k0 < K; k0 += 64) {
#pragma unroll
        for (int t = 0; t < 4; t++) {
            int rr = wave * 32 + t * 8;
            int r = rr + ri;
            gld16(A + (size_t)(m0 + r) * K + k0 + cg * 8, As + rr * 64);
            int br = n0 + r; if (br > N - 1) br = N - 1;
            gld16(B + (size_t)br * K + k0 + cg * 8, Bs + rr * 64);
        }
        __syncthreads();
#pragma unroll
        for (int kk = 0; kk < 64; kk += 32) {
            int jb = kk >> 3;
            bf16x8 af[4], bfr[4];
#pragma unroll
            for (int mt = 0; mt < 4; mt++) {
                int rA = wm + mt * 16 + lane15;
                af[mt] = *(bf16x8*)(As + rA * 64 + (((jb + quad) ^ (rA & 7)) << 3));
            }
#pragma unroll
            for (int nt = 0; nt < 4; nt++) {
                int rB = wn + nt * 16 + lane15;
                bfr[nt] = *(bf16x8*)(Bs + rB * 64 + (((jb + quad) ^ (rB & 7)) << 3));
            }
#pragma unroll
            for (int mt = 0; mt < 4; mt++)
#pragma unroll
                for (int nt = 0; nt < 4; nt++)
                    acc[mt][nt] = __builtin_amdgcn_mfma_f32_16x16x32_bf16(
                        af[mt], bfr[nt], acc[mt][nt], 0, 0, 0);
        }
        __syncthreads();
    }

    const float KLOG = 13.287712379549449f / 32.0f;  // log2(10000)/32

    // --- rope tiles -------------------------------------------------------
    if (mode == 8 && n0 == 2048) {                     // k-rope + broadcast
        if (wn == 0) {
#pragma unroll
            for (int mt = 0; mt < 4; mt++) {
                int row = m0 + wm + mt * 16 + quad * 4;
#pragma unroll
                for (int nt = 0; nt < 2; nt++) {
                    int i = nt * 16 + lane15;          // 0..31
                    float inv = exp2f(-(float)i * KLOG);
#pragma unroll
                    for (int r = 0; r < 4; r++) {
                        int tok = row + r;
                        float p = (float)positions[tok & (SLEN - 1)];
                        float sn, cs; sincosf(p * inv, &sn, &cs);
                        float t1 = acc[mt][nt][r], t2 = acc[mt][nt + 2][r];
                        float rot1 = t1 * cs - t2 * sn;
                        float rot2 = t2 * cs + t1 * sn;
                        size_t ob = (size_t)tok * 3072 + 128;
#pragma unroll
                        for (int hh = 0; hh < 16; hh++) {
                            o.c[ob + hh * 192 + i]      = (__bf16)rot1;
                            o.c[ob + hh * 192 + 32 + i] = (__bf16)rot2;
                        }
                    }
                }
            }
        }
        return;
    }
    if (mode == 9 && n0 >= 2048) {                     // q-rope (scaled)
        int hh = (n0 + wn - 2048) >> 6;
#pragma unroll
        for (int mt = 0; mt < 4; mt++) {
            int row = m0 + wm + mt * 16 + quad * 4;
#pragma unroll
            for (int nt = 0; nt < 2; nt++) {
                int i = nt * 16 + lane15;              // 0..31
                float inv = exp2f(-(float)i * KLOG);
#pragma unroll
                for (int r = 0; r < 4; r++) {
                    int tok = row + r;
                    float p = (float)positions[tok & (SLEN - 1)];
                    float sn, cs; sincosf(p * inv, &sn, &cs);
                    float t1 = acc[mt][nt][r], t2 = acc[mt][nt + 2][r];
                    size_t ob = (size_t)tok * 3072 + hh * 192 + 128;
                    o.a[ob + i]      = (__bf16)((t1 * cs - t2 * sn) * scale);
                    o.a[ob + 32 + i] = (__bf16)((t2 * cs + t1 * sn) * scale);
                }
            }
        }
        return;
    }

    // --- generic epilogues ------------------------------------------------
#pragma unroll
    for (int mt = 0; mt < 4; mt++) {
        int row = m0 + wm + mt * 16 + quad * 4;
#pragma unroll
        for (int nt = 0; nt < 4; nt++) {
            int col = n0 + wn + nt * 16 + lane15;
            if (col < N) {
#pragma unroll
                for (int r = 0; r < 4; r++) {
                    float v = acc[mt][nt][r];
                    size_t rw = (size_t)(row + r);
                    if (mode == 2) {
                        o.f[rw * N + col] = v;
                    } else if (mode == 8) {
                        if (col < 1536) o.a[rw * 1536 + col] = (__bf16)v;
                        else            o.b[rw * 512 + col - 1536] = (__bf16)v;
                    } else if (mode == 9) {
                        o.a[rw * 3072 + (col >> 7) * 192 + (col & 127)] =
                            (__bf16)(v * scale);
                    } else {  // 10
                        if (col < 2048)
                            o.a[rw * 3072 + (col >> 7) * 192 + (col & 127)] = (__bf16)v;
                        else {
                            int d = col - 2048;
                            o.b[((size_t)d * 2 + (rw >> 11)) * 2048 + (rw & 2047)] = (__bf16)v;
                        }
                    }
                }
            }
        }
    }
}

// ---------------------------------------------------------------------------
// Causal flash attention v6: occupancy restructure.
// Round-5 counters proved attn runs at ~1 block/CU (Occupancy 12.8% = 4.1
// waves/CU): 512 blocks on 256 CUs dispatch one-per-CU, so 1 wave/SIMD and
// the serial chain is fully exposed.  Fix: QBLK=64 (4 waves x 16 q-rows),
// KVBLK=32 for K/P (V still staged 64-wide on even tiles -- its LDS path is
// byte-identical to the proven kernel with ks := tile parity).
// LDS = 12K (Ks 32x192) + 16K (Vs 128x64) + 5K (Ps) = 33 KiB -> 4 blocks/CU;
// grid 1024 blocks = 4/CU co-resident = 16 waves/CU (launch_bounds(256,4)).
// T1 XCD grouping (round 5: FETCH 120->33 MB) and complementary (qt,31-qt)
// pairing preserved in 32-tile form.
// ---------------------------------------------------------------------------
__global__ __launch_bounds__(256, 4)
void mla_attn(const __bf16* __restrict__ Q, const __bf16* __restrict__ K,
              const __bf16* __restrict__ Vt, __bf16* __restrict__ O) {
    __shared__ __bf16 Ks[32 * 192];
    __shared__ __bf16 Vs[128 * 64];
    __shared__ __bf16 Ps[4][16][40];
    int tid = threadIdx.x, wave = tid >> 6, lane = tid & 63;
    int lane15 = lane & 15, quad = lane >> 4;

    // T1 remap: all 32 q-tile blocks of group g=(b,h) share lin%8 -> one XCD.
    int lin = blockIdx.x + (blockIdx.y << 5) + (blockIdx.z << 9);
    int xcd = lin & 7, slot = lin >> 3;        // slot 0..127
    int x = slot & 31;                          // q-tile member 0..31
    int g = xcd + ((slot >> 5) << 3);           // group 0..31
    int h = g & 15, b = g >> 4;

    int qt0 = (x & 1) ? (x >> 1) : (31 - (x >> 1));
    int qt = b ? (31 - qt0) : qt0;
    int q0 = qt * 64;
    const __bf16* Qb  = Q + (size_t)b * SLEN * 3072 + h * 192;
    const __bf16* Kb  = K + (size_t)b * SLEN * 3072 + h * 192;
    const __bf16* vtb = Vt + ((size_t)(h * 128) * 2 + b) * 2048;

    bf16x8 qf[6];
    {
        int qrow = q0 + wave * 16 + lane15;
#pragma unroll
        for (int kk = 0; kk < 6; kk++)
            qf[kk] = *(const bf16x8*)(Qb + (size_t)qrow * 3072 + kk * 32 + quad * 8);
    }
    bf16x8 ones;
#pragma unroll
    for (int e = 0; e < 8; e++) ones[e] = (__bf16)1.0f;

    f32x4 o_acc[8] = {};
    float m_i[4], l_i[4];
#pragma unroll
    for (int r = 0; r < 4; r++) { m_i[r] = -3.0e38f; l_i[r] = 0.0f; }

    int ntiles = 2 * qt + 2;                    // always even
    for (int t = 0; t < ntiles; t++) {
        int j0 = t * 32;
        // stage K (32x192), swizzled: 3 gld16/wave
#pragma unroll
        for (int tt = 0; tt < 3; tt++) {
            int sb = (wave * 3 + tt) * 64;
            int sl = sb + lane;
            int r = sl / 24;
            int c = sl - r * 24;
            int cgk = (c & ~7) | ((c & 7) ^ (r & 7));
            gld16(Kb + (size_t)(j0 + r) * 3072 + cgk * 8, Ks + sb * 8);
        }
        // stage V (128 d-rows x 64 tokens) on even tiles: 4 gld16/wave
        if (!(t & 1)) {
#pragma unroll
            for (int tt = 0; tt < 4; tt++) {
                int sb = (wave * 4 + tt) * 64;
                int sl = sb + lane;
                int r = sl >> 3, c = sl & 7;
                gld16(vtb + (size_t)r * 4096 + j0 + (c ^ (r & 7)) * 8, Vs + sb * 8);
            }
        }
        __syncthreads();

        // QK^T: 1 m-tile x 2 n-tiles
        f32x4 acc[2] = {};
        __builtin_amdgcn_s_setprio(1);
#pragma unroll
        for (int kk = 0; kk < 6; kk++) {
#pragma unroll
            for (int nt = 0; nt < 2; nt++) {
                int n = nt * 16 + lane15;
                int j = kk * 4 + quad;
                int cl = (j & ~7) | ((j & 7) ^ (n & 7));
                bf16x8 kf = *(bf16x8*)(Ks + n * 192 + cl * 8);
                acc[nt] = __builtin_amdgcn_mfma_f32_16x16x32_bf16(
                    qf[kk], kf, acc[nt], 0, 0, 0);
            }
        }
        __builtin_amdgcn_s_setprio(0);

        if (j0 >= q0) {  // causal mask (last two tiles)
            int rowg = q0 + wave * 16 + quad * 4;
#pragma unroll
            for (int nt = 0; nt < 2; nt++) {
                int colg = j0 + nt * 16 + lane15;
#pragma unroll
                for (int r = 0; r < 4; r++)
                    if (colg > rowg + r) acc[nt][r] = -3.0e38f;
            }
        }

        // threshold-max: slow path only when tile max exceeds m+24
        float mx[4];
        bool need = false;
#pragma unroll
        for (int r = 0; r < 4; r++) {
            float v = fmaxf(acc[0][r], acc[1][r]);
            mx[r] = v;
            need = need || (v > m_i[r] + 24.0f);
        }
        if (__any(need)) {
#pragma unroll
            for (int r = 0; r < 4; r++) {
                float v = mx[r];
#pragma unroll
                for (int d = 8; d >= 1; d >>= 1) v = fmaxf(v, __shfl_xor(v, d));
                float mn = fmaxf(m_i[r], v);
                float alpha = exp2f(m_i[r] - mn);
                m_i[r] = mn;
                l_i[r] *= alpha;
#pragma unroll
                for (int nt = 0; nt < 8; nt++) o_acc[nt][r] *= alpha;
            }
        }

        // P = exp2(acc - m), store to Ps (A-layout round-trip)
#pragma unroll
        for (int r = 0; r < 4; r++)
#pragma unroll
            for (int nt = 0; nt < 2; nt++) {
                float pp = exp2f(acc[nt][r] - m_i[r]);
                Ps[wave][quad * 4 + r][nt * 16 + lane15] = (__bf16)pp;
            }

        // PV + row-sum MFMA (V chunk = tile parity)
        f32x4 rs = {};
        __builtin_amdgcn_s_setprio(1);
        bf16x8 pf = *(bf16x8*)(&Ps[wave][lane15][quad * 8]);
        int j = ((t & 1) << 2) + quad;
#pragma unroll
        for (int nt = 0; nt < 8; nt++) {
            int nn = nt * 16 + lane15;
            bf16x8 vf = *(bf16x8*)(Vs + nn * 64 + ((j ^ (nn & 7)) * 8));
            o_acc[nt] = __builtin_amdgcn_mfma_f32_16x16x32_bf16(
                pf, vf, o_acc[nt], 0, 0, 0);
        }
        rs = __builtin_amdgcn_mfma_f32_16x16x32_bf16(pf, ones, rs, 0, 0, 0);
        __builtin_amdgcn_s_setprio(0);
#pragma unroll
        for (int r = 0; r < 4; r++) l_i[r] += rs[r];
        __syncthreads();
    }

    int tokb = b * SLEN + q0 + wave * 16 + quad * 4;
#pragma unroll
    for (int r = 0; r < 4; r++) {
        float inv_l = 1.0f / l_i[r];
        int tok = tokb + r;
#pragma unroll
        for (int nt = 0; nt < 8; nt++) {
            O[(size_t)tok * 2048 + h * 128 + nt * 16 + lane15] =
                (__bf16)(o_acc[nt][r] * inv_l);
        }
    }
}

// ---------------------------------------------------------------------------
extern "C" void kernel_launch(void* const* d_in, const int* in_sizes, int n_in,
                              void* d_out, int out_size, void* d_ws, size_t ws_size,
                              hipStream_t stream) {
    (void)in_sizes; (void)n_in; (void)out_size; (void)ws_size;
    const int* pos = (const int*)d_in[1];
    float* out = (float*)d_out;

    char* ws = (char*)d_ws;
    size_t off = 0;
    auto alloc = [&](size_t bytes) {
        char* p = ws + off;
        off += (bytes + 255) & ~(size_t)255;
        return p;
    };
    __bf16* x_bf  = (__bf16*)alloc(8388608ull * 2);
    __bf16* Wcat1 = (__bf16*)alloc(4325376ull * 2);  // Wqd | Wkvd | Wkr  (K=2048)
    __bf16* Wcat2 = (__bf16*)alloc(4718592ull * 2);  // Wqu | Wqr        (K=1536)
    __bf16* Wcat3 = (__bf16*)alloc(4194304ull * 2);  // Wku | Wvu        (K=512)
    __bf16* Wob   = (__bf16*)alloc(4194304ull * 2);
    __bf16* c_q   = (__bf16*)alloc(4096ull * 1536 * 2);
    __bf16* c_kv  = (__bf16*)alloc(4096ull * 512 * 2);
    __bf16* v_t   = (__bf16*)alloc(4096ull * 2048 * 2);
    __bf16* q_all = (__bf16*)alloc(4096ull * 3072 * 2);
    __bf16* k_all = (__bf16*)alloc(4096ull * 3072 * 2);
    __bf16* attn_o = (__bf16*)c_q;   // overlays c_q+c_kv (exactly 16.78 MB)

    const float scale_l2 = 1.4426950408889634f / sqrtf(192.0f);
    dim3 blk(256);

    CvArgs cv;
    cv.src[0] = (const float*)d_in[0]; cv.dst[0] = x_bf;
    cv.src[1] = (const float*)d_in[2]; cv.dst[1] = Wcat1;
    cv.src[2] = (const float*)d_in[5]; cv.dst[2] = Wcat1 + 3145728;
    cv.src[3] = (const float*)d_in[8]; cv.dst[3] = Wcat1 + 4194304;
    cv.src[4] = (const float*)d_in[3]; cv.dst[4] = Wcat2;
    cv.src[5] = (const float*)d_in[4]; cv.dst[5] = Wcat2 + 3145728;
    cv.src[6] = (const float*)d_in[6]; cv.dst[6] = Wcat3;
    cv.src[7] = (const float*)d_in[7]; cv.dst[7] = Wcat3 + 1048576;
    cv.src[8] = (const float*)d_in[9]; cv.dst[8] = Wob;
    long ns[9] = {8388608, 3145728, 1048576, 131072, 3145728, 1572864,
                  1048576, 1048576, 4194304};
    cv.cum[0] = 0;
    for (int i = 0; i < 9; i++) cv.cum[i + 1] = cv.cum[i] + ns[i];
    convert_all<<<dim3((unsigned)(cv.cum[9] / 2048)), blk, 0, stream>>>(cv);

    Outs o1 = { c_q, c_kv, k_all, nullptr };
    gemm_nt<<<dim3(32, 17), blk, 0, stream>>>(x_bf, Wcat1, o1, pos, 4096, 2112, 2048, 8, 1.0f);
    Outs o2 = { q_all, nullptr, nullptr, nullptr };
    gemm_nt<<<dim3(32, 24), blk, 0, stream>>>(c_q, Wcat2, o2, pos, 4096, 3072, 1536, 9, scale_l2);
    Outs o3 = { k_all, v_t, nullptr, nullptr };
    gemm_nt<<<dim3(32, 32), blk, 0, stream>>>(c_kv, Wcat3, o3, pos, 4096, 4096, 512, 10, 1.0f);
    mla_attn<<<dim3(32, 16, 2), blk, 0, stream>>>(q_all, k_all, v_t, attn_o);
    Outs o4 = { nullptr, nullptr, nullptr, out };
    gemm_nt<<<dim3(32, 16), blk, 0, stream>>>(attn_o, Wob, o4, pos, 4096, 2048, 2048, 2, 1.0f);
}